// Round 2
// baseline (296.537 us; speedup 1.0000x reference)
//
#include <hip/hip_runtime.h>
#include <hip/hip_bf16.h>

#define NB 128
#define NP 8732
#define NO 32
#define NC 21

// ---------------- workspace layout ----------------
// [0, 32768)        : unsigned long long packed[NB*NO]  (per-object argmax over priors)
// [32768, 33280)    : int npos[NB]
// [33280, 36352)    : double accb[NB][3]  (0=pos_conf, 1=loc, 2=hard_neg)
// [36352, 36356)    : int donecnt          (k_topk last-block counter)
// [36608, +NB*NP*4) : int code[NB*NP]      (obj | matched-flag<<8)
// [..., +NB*NP*4)   : float confneg[NB*NP]

__global__ __launch_bounds__(256) void k_init(int* ws) {
    int i = blockIdx.x * 256 + threadIdx.x;
    const int n = 36608 / 4;
    if (i < n) ws[i] = 0;
}

// 2 priors per thread (grid.x=18 -> 9216 waves, ~8 waves/SIMD for latency hiding).
// Phase 1: per-object local max into fully-unrolled register array (+ tie flags).
// Phase 2: 32 INDEPENDENT 6-deep shuffle chains (pipelined, not serial-dependent),
//          then per-j ballots resolve smallest-p tie-break; atomicMax packed key.
__global__ __launch_bounds__(256) void k_match(const float* __restrict__ boxes,
                                               const float* __restrict__ priors,
                                               int* __restrict__ code,
                                               unsigned long long* __restrict__ packed) {
    int b = blockIdx.y;
    int tid = threadIdx.x;
    int lane = tid & 63;
    int bb = blockIdx.x * 512;

    __shared__ float4 sbox[NO];
    if (tid < NO)
        sbox[tid] = ((const float4*)(boxes + (size_t)b * NO * 4))[tid];
    __syncthreads();

    float px1[2], py1[2], px2[2], py2[2], pa[2];
#pragma unroll
    for (int j = 0; j < 2; ++j) {
        int p = bb + 256 * j + tid;
        int pp = p < NP ? p : NP - 1;   // tail clamp: dup of 8731 always loses ties (larger p)
        float4 pr = ((const float4*)priors)[pp];
        px1[j] = pr.x - pr.z * 0.5f; py1[j] = pr.y - pr.w * 0.5f;
        px2[j] = pr.x + pr.z * 0.5f; py2[j] = pr.y + pr.w * 0.5f;
        pa[j]  = (px2[j] - px1[j]) * (py2[j] - py1[j]);
    }

    float bestv0 = -1.0f, bestv1 = -1.0f;
    int   besto0 = 0,     besto1 = 0;
    float locmax[NO];              // static-indexed (full unroll) -> stays in VGPRs
    unsigned f0 = 0u, f1 = 0u;     // bit o set: j's iou achieved locmax[o]

#pragma unroll
    for (int o = 0; o < NO; ++o) {
        float4 bx = sbox[o];
        float a1 = (bx.z - bx.x) * (bx.w - bx.y);

        float lx0 = fmaxf(bx.x, px1[0]), ly0 = fmaxf(bx.y, py1[0]);
        float hx0 = fminf(bx.z, px2[0]), hy0 = fminf(bx.w, py2[0]);
        float in0 = fmaxf(hx0 - lx0, 0.0f) * fmaxf(hy0 - ly0, 0.0f);
        float i0  = in0 / (a1 + pa[0] - in0);     // same expr/order as reference

        float lx1 = fmaxf(bx.x, px1[1]), ly1 = fmaxf(bx.y, py1[1]);
        float hx1 = fminf(bx.z, px2[1]), hy1 = fminf(bx.w, py2[1]);
        float in1 = fmaxf(hx1 - lx1, 0.0f) * fmaxf(hy1 - ly1, 0.0f);
        float i1  = in1 / (a1 + pa[1] - in1);

        if (i0 > bestv0) { bestv0 = i0; besto0 = o; }  // first max wins
        if (i1 > bestv1) { bestv1 = i1; besto1 = o; }

        float lm = fmaxf(i0, i1);
        locmax[o] = lm;
        f0 |= (i0 == lm ? 1u : 0u) << o;
        f1 |= (i1 == lm ? 1u : 0u) << o;
    }

    int wl0 = bb + (tid & ~63);    // p of (this wave, lane 0, j=0)

#pragma unroll
    for (int o = 0; o < NO; ++o) {
        float m = locmax[o];
        for (int s = 32; s > 0; s >>= 1)
            m = fmaxf(m, __shfl_xor(m, s, 64));
        // smallest p among ties: j=0 block strictly precedes j=1; within j, lane order = p order
        unsigned long long b0 = __ballot(((f0 >> o) & 1u) && (locmax[o] == m));
        unsigned long long b1 = __ballot(((f1 >> o) & 1u) && (locmax[o] == m));
        if (lane == 0) {
            unsigned p;
            if (b0) p = (unsigned)(wl0 + (__ffsll((unsigned long long)b0) - 1));
            else    p = (unsigned)(wl0 + 256 + (__ffsll((unsigned long long)b1) - 1));
            unsigned long long key =
                ((unsigned long long)__float_as_uint(m) << 32) |
                (unsigned long long)(0xFFFFFFFFu - p);
            atomicMax(&packed[b * NO + o], key);
        }
    }

    {
        int p0 = bb + tid;
        int p1 = bb + 256 + tid;
        if (p0 < NP) code[(size_t)b * NP + p0] = besto0 | (bestv0 >= 0.5f ? 256 : 0);
        if (p1 < NP) code[(size_t)b * NP + p1] = besto1 | (bestv1 >= 0.5f ? 256 : 0);
    }
}

// Scores staged through LDS with coalesced float4 loads.
// Forced matches (formerly k_force) merged in: 32 broadcast compares, last-o-wins.
__global__ __launch_bounds__(256) void k_loss(const float* __restrict__ plocs,
                                              const float* __restrict__ scores,
                                              const float* __restrict__ boxes,
                                              const int* __restrict__ labels,
                                              const float* __restrict__ priors,
                                              const int* __restrict__ code,
                                              const unsigned long long* __restrict__ packed,
                                              float* __restrict__ confneg,
                                              int* __restrict__ npos,
                                              double* __restrict__ accb) {
    __shared__ float srow[256 * NC];  // 21504 B
    __shared__ unsigned spfl[NO];     // forced prior per object
    int b = blockIdx.y;
    int p0 = blockIdx.x * 256;
    int cnt = NP - p0; if (cnt > 256) cnt = 256;
    int nf4 = cnt * NC / 4;  // exact: 4 | cnt*21 for cnt in {256, 28}
    const float4* src4 = (const float4*)(scores + ((size_t)b * NP + p0) * NC);
    for (int i = threadIdx.x; i < nf4; i += 256)
        ((float4*)srow)[i] = src4[i];
    if (threadIdx.x < NO) {
        unsigned long long pk = packed[b * NO + threadIdx.x];
        spfl[threadIdx.x] = 0xFFFFFFFFu - (unsigned)(pk & 0xFFFFFFFFull);
    }
    __syncthreads();

    int p = p0 + threadIdx.x;
    float posconf = 0.0f, locpart = 0.0f;
    int isp = 0;

    if (p < NP) {
        int cd = code[(size_t)b * NP + p];
        int obj = cd & 255;
        int mat = cd >> 8;
#pragma unroll
        for (int o = 0; o < NO; ++o)
            if (spfl[o] == (unsigned)p) { obj = o; mat = 1; }  // last o wins (scatter semantics)
        int lbl = mat ? labels[b * NO + obj] : 0;

        const float* s = srow + threadIdx.x * NC;  // stride 21: bank-conflict-free
        float m = s[0];
#pragma unroll
        for (int c = 1; c < NC; ++c) m = fmaxf(m, s[c]);
        float sum = 0.0f;
#pragma unroll
        for (int c = 0; c < NC; ++c) sum += __expf(s[c] - m);
        float conf = m + __logf(sum) - s[lbl];

        if (lbl != 0) {
            isp = 1;
            posconf = conf;
            float4 bx = ((const float4*)boxes)[b * NO + obj];
            float4 pr = ((const float4*)priors)[p];
            float cx = (bx.x + bx.z) * 0.5f, cy = (bx.y + bx.w) * 0.5f;
            float w = bx.z - bx.x, h = bx.w - bx.y;
            float gx = (cx - pr.x) / (pr.z * 0.1f);
            float gy = (cy - pr.y) / (pr.w * 0.1f);
            float gw = __logf(w / pr.z) * 5.0f;
            float gh = __logf(h / pr.w) * 5.0f;
            float4 pl = ((const float4*)plocs)[(size_t)b * NP + p];
            locpart = fabsf(pl.x - gx) + fabsf(pl.y - gy) +
                      fabsf(pl.z - gw) + fabsf(pl.w - gh);
        }
        confneg[(size_t)b * NP + p] = isp ? 0.0f : conf;
    }

    // wave shuffle reduce, then 4-wave LDS combine, one barrier
    for (int s = 32; s > 0; s >>= 1) {
        posconf += __shfl_xor(posconf, s, 64);
        locpart += __shfl_xor(locpart, s, 64);
        isp     += __shfl_xor(isp, s, 64);
    }
    __shared__ float w0[4], w1[4];
    __shared__ int wc[4];
    int wid = threadIdx.x >> 6, lane = threadIdx.x & 63;
    if (lane == 0) { w0[wid] = posconf; w1[wid] = locpart; wc[wid] = isp; }
    __syncthreads();
    if (threadIdx.x == 0) {
        float t0 = w0[0] + w0[1] + w0[2] + w0[3];
        float t1 = w1[0] + w1[1] + w1[2] + w1[3];
        int   tc = wc[0] + wc[1] + wc[2] + wc[3];
        atomicAdd(&npos[b], tc);
        atomicAdd(&accb[b * 3 + 0], (double)t0);  // 34 blocks per address
        atomicAdd(&accb[b * 3 + 1], (double)t1);
    }
}

// Exact k-th-largest by bit bisection; one block per image.
// Last block (device-scope counter) also does the final cross-image reduction
// (formerly k_final).
__global__ __launch_bounds__(1024) void k_topk(const float* __restrict__ confneg,
                                               const int* __restrict__ npos,
                                               double* __restrict__ accb,
                                               int* __restrict__ donecnt,
                                               float* __restrict__ out) {
    __shared__ int   si[16];
    __shared__ double sd[16];
    __shared__ int   sbcast;
    int tid = threadIdx.x, b = blockIdx.x;
    int lane = tid & 63, wid = tid >> 6;

    const float* src = confneg + (size_t)b * NP;
    float val[9];
#pragma unroll
    for (int j = 0; j < 9; ++j) {
        int i = tid + j * 1024;
        val[j] = (i < NP) ? src[i] : 0.0f;  // 0 never counts (cand>0)
    }
    int k = npos[b] * 3;
    if (k > NP) k = NP;

    if (k > 0) {  // block-uniform; accb[b*3+2] stays 0 from k_init when k<=0
        unsigned T = 0;
        for (int bit = 30; bit >= 0; --bit) {
            unsigned cand = T | (1u << bit);
            int cnt = 0;
#pragma unroll
            for (int j = 0; j < 9; ++j)
                cnt += (__float_as_uint(val[j]) >= cand) ? 1 : 0;
            for (int s = 32; s > 0; s >>= 1) cnt += __shfl_xor(cnt, s, 64);
            if (lane == 0) si[wid] = cnt;
            __syncthreads();
            if (tid == 0) {
                int t = 0;
                for (int w = 0; w < 16; ++w) t += si[w];
                sbcast = t;
            }
            __syncthreads();
            if (sbcast >= k) T = cand;  // uniform decision
        }

        int cgt = 0;
        double sgt = 0.0;
#pragma unroll
        for (int j = 0; j < 9; ++j) {
            unsigned u = __float_as_uint(val[j]);
            if (u > T) { cgt++; sgt += (double)val[j]; }
        }
        for (int s = 32; s > 0; s >>= 1) {
            cgt += __shfl_xor(cgt, s, 64);
            sgt += __shfl_xor(sgt, s, 64);
        }
        if (lane == 0) { si[wid] = cgt; sd[wid] = sgt; }
        __syncthreads();
        if (tid == 0) {
            int cg = 0; double sg = 0.0;
            for (int w = 0; w < 16; ++w) { cg += si[w]; sg += sd[w]; }
            accb[b * 3 + 2] = sg + (double)(k - cg) * (double)__uint_as_float(T);
        }
    }

    // ---- last-block final reduction (replaces k_final) ----
    __shared__ int samlast;
    if (tid == 0) {
        __threadfence();                       // make accb[b*3+2] store visible device-wide
        int prev = atomicAdd(donecnt, 1);      // device-scope by default
        samlast = (prev == NB - 1) ? 1 : 0;
    }
    __syncthreads();
    if (!samlast) return;
    __threadfence();

    double pc = 0.0, lc = 0.0, hn = 0.0, np_ = 0.0;
    if (tid < NB) {
        pc  = accb[tid * 3 + 0];                    // written by k_loss (prior kernel): safe
        lc  = accb[tid * 3 + 1];
        hn  = atomicAdd(&accb[tid * 3 + 2], 0.0);   // written by peer blocks: atomic read
        np_ = (double)npos[tid];
    }
    if (tid < 128) {
        for (int s = 32; s > 0; s >>= 1) {
            pc  += __shfl_xor(pc, s, 64);
            lc  += __shfl_xor(lc, s, 64);
            hn  += __shfl_xor(hn, s, 64);
            np_ += __shfl_xor(np_, s, 64);
        }
        if (lane == 0) { sd[wid * 4 + 0] = pc; sd[wid * 4 + 1] = lc;
                         sd[wid * 4 + 2] = hn; sd[wid * 4 + 3] = np_; }
    }
    __syncthreads();
    if (tid == 0) {
        double P = sd[0] + sd[4];
        double L = sd[1] + sd[5];
        double H = sd[2] + sd[6];
        double nt = sd[3] + sd[7];
        out[0] = (float)((H + P) / nt + L / (nt * 4.0));
    }
}

extern "C" void kernel_launch(void* const* d_in, const int* in_sizes, int n_in,
                              void* d_out, int out_size, void* d_ws, size_t ws_size,
                              hipStream_t stream) {
    const float* plocs  = (const float*)d_in[0];
    const float* scores = (const float*)d_in[1];
    const float* boxes  = (const float*)d_in[2];
    const int*   labels = (const int*)d_in[3];
    const float* priors = (const float*)d_in[4];
    float* out = (float*)d_out;

    char* ws = (char*)d_ws;
    unsigned long long* packed = (unsigned long long*)ws;
    int*    npos    = (int*)(ws + 32768);
    double* accb    = (double*)(ws + 33280);
    int*    donecnt = (int*)(ws + 36352);
    int*    code    = (int*)(ws + 36608);
    float*  confneg = (float*)(ws + 36608 + (size_t)NB * NP * 4);

    hipLaunchKernelGGL(k_init, dim3((36608 / 4 + 255) / 256), dim3(256), 0, stream, (int*)ws);
    hipLaunchKernelGGL(k_match, dim3((NP + 511) / 512, NB), dim3(256), 0, stream,
                       boxes, priors, code, packed);
    hipLaunchKernelGGL(k_loss, dim3((NP + 255) / 256, NB), dim3(256), 0, stream,
                       plocs, scores, boxes, labels, priors, code, packed, confneg, npos, accb);
    hipLaunchKernelGGL(k_topk, dim3(NB), dim3(1024), 0, stream, confneg, npos, accb, donecnt, out);
}

// Round 3
// 236.281 us; speedup vs baseline: 1.2550x; 1.2550x over previous
//
#include <hip/hip_runtime.h>
#include <hip/hip_bf16.h>

#define NB 128
#define NP 8732
#define NO 32
#define NC 21

// ---------------- workspace layout ----------------
// [0, 32768)        : unsigned long long packed[NB*NO]  (per-object argmax over priors)
// [32768, 33280)    : int npos[NB]
// [33280, 36352)    : double accb[NB][3]  (0=pos_conf, 1=loc, 2=hard_neg)
// [36352, 36356)    : int donecnt          (k_topk last-block counter)
// [36608, +NB*NP*4) : int code[NB*NP]      (obj | matched-flag<<8)
// [..., +NB*NP*4)   : float confneg[NB*NP]

__global__ __launch_bounds__(256) void k_init(int* ws) {
    int i = blockIdx.x * 256 + threadIdx.x;
    const int n = 36608 / 4;
    if (i < n) ws[i] = 0;
}

// Full wave64 max via DPP (VALU pipe, ~4cy/step) instead of ds_permute shuffles
// (~30cy/step). Result broadcast via readlane(63). Exact for IoU>=0: invalid-lane
// fill (old or 0.0) is identity under fmax.
__device__ __forceinline__ float wave64_max_dpp(float m) {
    int v;
    v = __builtin_amdgcn_update_dpp(__float_as_int(m), __float_as_int(m), 0x111, 0xf, 0xf, false); // row_shr:1
    m = fmaxf(m, __int_as_float(v));
    v = __builtin_amdgcn_update_dpp(__float_as_int(m), __float_as_int(m), 0x112, 0xf, 0xf, false); // row_shr:2
    m = fmaxf(m, __int_as_float(v));
    v = __builtin_amdgcn_update_dpp(__float_as_int(m), __float_as_int(m), 0x114, 0xf, 0xf, false); // row_shr:4
    m = fmaxf(m, __int_as_float(v));
    v = __builtin_amdgcn_update_dpp(__float_as_int(m), __float_as_int(m), 0x118, 0xf, 0xf, false); // row_shr:8
    m = fmaxf(m, __int_as_float(v));
    v = __builtin_amdgcn_update_dpp(__float_as_int(m), __float_as_int(m), 0x142, 0xf, 0xf, false); // row_bcast:15
    m = fmaxf(m, __int_as_float(v));
    v = __builtin_amdgcn_update_dpp(__float_as_int(m), __float_as_int(m), 0x143, 0xf, 0xf, false); // row_bcast:31
    m = fmaxf(m, __int_as_float(v));
    return __int_as_float(__builtin_amdgcn_readlane(__float_as_int(m), 63));  // lane63 = full max
}

// 4 priors per thread, strided by 256 within the block (coalesced). Round-1
// structure (VGPR-lean, occupancy ~30%); per-object reduce now DPP-based.
__global__ __launch_bounds__(256) void k_match(const float* __restrict__ boxes,
                                               const float* __restrict__ priors,
                                               int* __restrict__ code,
                                               unsigned long long* __restrict__ packed) {
    int b = blockIdx.y;
    int tid = threadIdx.x;
    int base = blockIdx.x * 1024 + tid;
    int lane = tid & 63;

    __shared__ float4 sbox[NO];
    if (tid < NO)
        sbox[tid] = ((const float4*)(boxes + (size_t)b * NO * 4))[tid];
    __syncthreads();

    float px1[4], py1[4], px2[4], py2[4], pa[4];
    float bestv[4];
    int   besto[4];
#pragma unroll
    for (int j = 0; j < 4; ++j) {
        int p = base + 256 * j;
        int pp = p < NP ? p : NP - 1;   // tail clamp: dup of 8731 sits at a later (j,lane)
                                        // position with equal iou -> always loses the
                                        // smallest-p tie-break to the real 8731
        float4 pr = ((const float4*)priors)[pp];
        px1[j] = pr.x - pr.z * 0.5f; py1[j] = pr.y - pr.w * 0.5f;
        px2[j] = pr.x + pr.z * 0.5f; py2[j] = pr.y + pr.w * 0.5f;
        pa[j]  = (px2[j] - px1[j]) * (py2[j] - py1[j]);
        bestv[j] = -1.0f; besto[j] = 0;
    }

    // p of (lane 0, j=0) in this wave; within a wave p = wavep0 + 256*j + lane,
    // so p is monotone in (j, lane) -> first set ballot bit == smallest p.
    int wavep0 = blockIdx.x * 1024 + (tid & ~63);

#pragma unroll 2
    for (int o = 0; o < NO; ++o) {
        float4 bx = sbox[o];
        float a1 = (bx.z - bx.x) * (bx.w - bx.y);
        float iou[4];
#pragma unroll
        for (int j = 0; j < 4; ++j) {
            float lx = fmaxf(bx.x, px1[j]), ly = fmaxf(bx.y, py1[j]);
            float hx = fminf(bx.z, px2[j]), hy = fminf(bx.w, py2[j]);
            float iw = fmaxf(hx - lx, 0.0f), ih = fmaxf(hy - ly, 0.0f);
            float inter = iw * ih;
            iou[j] = inter / (a1 + pa[j] - inter);   // same expr/order as reference
            if (iou[j] > bestv[j]) { bestv[j] = iou[j]; besto[j] = o; }  // first max wins
        }
        // phase A: wave max of iou (DPP, VALU-pipe latency)
        float m = wave64_max_dpp(fmaxf(fmaxf(iou[0], iou[1]), fmaxf(iou[2], iou[3])));
        // phase B: tie-break to smallest p via ballots + scalar-pipe resolve
        unsigned long long b0 = __ballot(iou[0] == m);
        unsigned long long b1 = __ballot(iou[1] == m);
        unsigned long long b2 = __ballot(iou[2] == m);
        unsigned long long b3 = __ballot(iou[3] == m);
        if (lane == 0) {
            unsigned long long bb; int jj;
            if (b0)      { bb = b0; jj = 0; }
            else if (b1) { bb = b1; jj = 1; }
            else if (b2) { bb = b2; jj = 2; }
            else         { bb = b3; jj = 3; }
            unsigned p = (unsigned)(wavep0 + 256 * jj) + (unsigned)(__ffsll(bb) - 1);
            unsigned long long key =
                ((unsigned long long)__float_as_uint(m) << 32) |
                (unsigned long long)(0xFFFFFFFFu - p);
            atomicMax(&packed[b * NO + o], key);
        }
    }
#pragma unroll
    for (int j = 0; j < 4; ++j) {
        int p = base + 256 * j;
        if (p < NP)
            code[(size_t)b * NP + p] = besto[j] | (bestv[j] >= 0.5f ? 256 : 0);
    }
}

// Scores staged through LDS with coalesced float4 loads.
// Forced matches (formerly k_force) merged in: 32 broadcast compares, last-o-wins.
__global__ __launch_bounds__(256) void k_loss(const float* __restrict__ plocs,
                                              const float* __restrict__ scores,
                                              const float* __restrict__ boxes,
                                              const int* __restrict__ labels,
                                              const float* __restrict__ priors,
                                              const int* __restrict__ code,
                                              const unsigned long long* __restrict__ packed,
                                              float* __restrict__ confneg,
                                              int* __restrict__ npos,
                                              double* __restrict__ accb) {
    __shared__ float srow[256 * NC];  // 21504 B
    __shared__ unsigned spfl[NO];     // forced prior per object
    int b = blockIdx.y;
    int p0 = blockIdx.x * 256;
    int cnt = NP - p0; if (cnt > 256) cnt = 256;
    int nf4 = cnt * NC / 4;  // exact: 4 | cnt*21 for cnt in {256, 28}
    const float4* src4 = (const float4*)(scores + ((size_t)b * NP + p0) * NC);
    for (int i = threadIdx.x; i < nf4; i += 256)
        ((float4*)srow)[i] = src4[i];
    if (threadIdx.x < NO) {
        unsigned long long pk = packed[b * NO + threadIdx.x];
        spfl[threadIdx.x] = 0xFFFFFFFFu - (unsigned)(pk & 0xFFFFFFFFull);
    }
    __syncthreads();

    int p = p0 + threadIdx.x;
    float posconf = 0.0f, locpart = 0.0f;
    int isp = 0;

    if (p < NP) {
        int cd = code[(size_t)b * NP + p];
        int obj = cd & 255;
        int mat = cd >> 8;
#pragma unroll
        for (int o = 0; o < NO; ++o)
            if (spfl[o] == (unsigned)p) { obj = o; mat = 1; }  // last o wins (scatter semantics)
        int lbl = mat ? labels[b * NO + obj] : 0;

        const float* s = srow + threadIdx.x * NC;  // stride 21: bank-conflict-free
        float m = s[0];
#pragma unroll
        for (int c = 1; c < NC; ++c) m = fmaxf(m, s[c]);
        float sum = 0.0f;
#pragma unroll
        for (int c = 0; c < NC; ++c) sum += __expf(s[c] - m);
        float conf = m + __logf(sum) - s[lbl];

        if (lbl != 0) {
            isp = 1;
            posconf = conf;
            float4 bx = ((const float4*)boxes)[b * NO + obj];
            float4 pr = ((const float4*)priors)[p];
            float cx = (bx.x + bx.z) * 0.5f, cy = (bx.y + bx.w) * 0.5f;
            float w = bx.z - bx.x, h = bx.w - bx.y;
            float gx = (cx - pr.x) / (pr.z * 0.1f);
            float gy = (cy - pr.y) / (pr.w * 0.1f);
            float gw = __logf(w / pr.z) * 5.0f;
            float gh = __logf(h / pr.w) * 5.0f;
            float4 pl = ((const float4*)plocs)[(size_t)b * NP + p];
            locpart = fabsf(pl.x - gx) + fabsf(pl.y - gy) +
                      fabsf(pl.z - gw) + fabsf(pl.w - gh);
        }
        confneg[(size_t)b * NP + p] = isp ? 0.0f : conf;
    }

    // wave shuffle reduce, then 4-wave LDS combine, one barrier
    for (int s = 32; s > 0; s >>= 1) {
        posconf += __shfl_xor(posconf, s, 64);
        locpart += __shfl_xor(locpart, s, 64);
        isp     += __shfl_xor(isp, s, 64);
    }
    __shared__ float w0[4], w1[4];
    __shared__ int wc[4];
    int wid = threadIdx.x >> 6, lane = threadIdx.x & 63;
    if (lane == 0) { w0[wid] = posconf; w1[wid] = locpart; wc[wid] = isp; }
    __syncthreads();
    if (threadIdx.x == 0) {
        float t0 = w0[0] + w0[1] + w0[2] + w0[3];
        float t1 = w1[0] + w1[1] + w1[2] + w1[3];
        int   tc = wc[0] + wc[1] + wc[2] + wc[3];
        atomicAdd(&npos[b], tc);
        atomicAdd(&accb[b * 3 + 0], (double)t0);  // 34 blocks per address
        atomicAdd(&accb[b * 3 + 1], (double)t1);
    }
}

// Exact k-th-largest by bit bisection; one block per image.
// Count reduce = ballot+popcount (no cross-lane latency); per-wave counts
// double-buffered in LDS -> ONE barrier per bisection step.
// Last block (device-scope counter) also does the final cross-image reduction.
__global__ __launch_bounds__(1024) void k_topk(const float* __restrict__ confneg,
                                               const int* __restrict__ npos,
                                               double* __restrict__ accb,
                                               int* __restrict__ donecnt,
                                               float* __restrict__ out) {
    __shared__ int   si2[2][16];
    __shared__ int   si[16];
    __shared__ double sd[16];
    int tid = threadIdx.x, b = blockIdx.x;
    int lane = tid & 63, wid = tid >> 6;

    const float* src = confneg + (size_t)b * NP;
    float val[9];
#pragma unroll
    for (int j = 0; j < 9; ++j) {
        int i = tid + j * 1024;
        val[j] = (i < NP) ? src[i] : 0.0f;  // 0 never counts (cand>0)
    }
    int k = npos[b] * 3;
    if (k > NP) k = NP;

    if (k > 0) {  // block-uniform; accb[b*3+2] stays 0 from k_init when k<=0
        unsigned T = 0;
        int par = 0;
        for (int bit = 30; bit >= 0; --bit) {
            unsigned cand = T | (1u << bit);
            int cnt = 0;
#pragma unroll
            for (int j = 0; j < 9; ++j)
                cnt += __popcll(__ballot(__float_as_uint(val[j]) >= cand));
            if (lane == 0) si2[par][wid] = cnt;
            __syncthreads();
            int t = 0;
#pragma unroll
            for (int w = 0; w < 16; ++w) t += si2[par][w];  // broadcast reads, all threads
            par ^= 1;           // next write goes to other buffer: no 2nd barrier needed
            if (t >= k) T = cand;  // uniform decision
        }

        int cgt = 0;
        double sgt = 0.0;
#pragma unroll
        for (int j = 0; j < 9; ++j) {
            unsigned u = __float_as_uint(val[j]);
            if (u > T) { cgt++; sgt += (double)val[j]; }
        }
        for (int s = 32; s > 0; s >>= 1) {
            cgt += __shfl_xor(cgt, s, 64);
            sgt += __shfl_xor(sgt, s, 64);
        }
        if (lane == 0) { si[wid] = cgt; sd[wid] = sgt; }
        __syncthreads();
        if (tid == 0) {
            int cg = 0; double sg = 0.0;
            for (int w = 0; w < 16; ++w) { cg += si[w]; sg += sd[w]; }
            accb[b * 3 + 2] = sg + (double)(k - cg) * (double)__uint_as_float(T);
        }
    }

    // ---- last-block final reduction (replaces k_final) ----
    __shared__ int samlast;
    if (tid == 0) {
        __threadfence();                       // make accb[b*3+2] store visible device-wide
        int prev = atomicAdd(donecnt, 1);      // device-scope by default
        samlast = (prev == NB - 1) ? 1 : 0;
    }
    __syncthreads();
    if (!samlast) return;
    __threadfence();

    double pc = 0.0, lc = 0.0, hn = 0.0, np_ = 0.0;
    if (tid < NB) {
        pc  = accb[tid * 3 + 0];                    // written by k_loss (prior kernel): safe
        lc  = accb[tid * 3 + 1];
        hn  = atomicAdd(&accb[tid * 3 + 2], 0.0);   // written by peer blocks: atomic read
        np_ = (double)npos[tid];
    }
    if (tid < 128) {
        for (int s = 32; s > 0; s >>= 1) {
            pc  += __shfl_xor(pc, s, 64);
            lc  += __shfl_xor(lc, s, 64);
            hn  += __shfl_xor(hn, s, 64);
            np_ += __shfl_xor(np_, s, 64);
        }
        if (lane == 0) { sd[wid * 4 + 0] = pc; sd[wid * 4 + 1] = lc;
                         sd[wid * 4 + 2] = hn; sd[wid * 4 + 3] = np_; }
    }
    __syncthreads();
    if (tid == 0) {
        double P = sd[0] + sd[4];
        double L = sd[1] + sd[5];
        double H = sd[2] + sd[6];
        double nt = sd[3] + sd[7];
        out[0] = (float)((H + P) / nt + L / (nt * 4.0));
    }
}

extern "C" void kernel_launch(void* const* d_in, const int* in_sizes, int n_in,
                              void* d_out, int out_size, void* d_ws, size_t ws_size,
                              hipStream_t stream) {
    const float* plocs  = (const float*)d_in[0];
    const float* scores = (const float*)d_in[1];
    const float* boxes  = (const float*)d_in[2];
    const int*   labels = (const int*)d_in[3];
    const float* priors = (const float*)d_in[4];
    float* out = (float*)d_out;

    char* ws = (char*)d_ws;
    unsigned long long* packed = (unsigned long long*)ws;
    int*    npos    = (int*)(ws + 32768);
    double* accb    = (double*)(ws + 33280);
    int*    donecnt = (int*)(ws + 36352);
    int*    code    = (int*)(ws + 36608);
    float*  confneg = (float*)(ws + 36608 + (size_t)NB * NP * 4);

    hipLaunchKernelGGL(k_init, dim3((36608 / 4 + 255) / 256), dim3(256), 0, stream, (int*)ws);
    hipLaunchKernelGGL(k_match, dim3((NP + 1023) / 1024, NB), dim3(256), 0, stream,
                       boxes, priors, code, packed);
    hipLaunchKernelGGL(k_loss, dim3((NP + 255) / 256, NB), dim3(256), 0, stream,
                       plocs, scores, boxes, labels, priors, code, packed, confneg, npos, accb);
    hipLaunchKernelGGL(k_topk, dim3(NB), dim3(1024), 0, stream, confneg, npos, accb, donecnt, out);
}